// Round 13
// baseline (330.676 us; speedup 1.0000x reference)
//
#include <hip/hip_runtime.h>
#include <hip/hip_bf16.h>

// ---------------------------------------------------------------------------
// TernaryCIFAR10Net on MI355X — Round 13:
//   conv2/conv3 occupancy fix: 512-thread blocks (8 waves), per-wave tile
//   MT=2 x NT=4 -> 64 acc regs (was 128); __launch_bounds__(512,4) caps
//   VGPR at 128 -> 2 blocks/CU resident (was 1). Same per-block work,
//   staging-once, B double-buffered, A per-plane loads.
//   conv1 (i8 MFMA K-free), fc1 (bf16 MFMA split-K), fc2, ternarize
//   unchanged from R12.
// ---------------------------------------------------------------------------

typedef __attribute__((ext_vector_type(8))) short short8;
typedef __attribute__((ext_vector_type(4))) float f32x4;
typedef __attribute__((ext_vector_type(4))) int i32x4;

__device__ __forceinline__ unsigned short f2bf(float x) {
    unsigned u = __float_as_uint(x);
    return (unsigned short)((u + 0x7fffu + ((u >> 16) & 1u)) >> 16);  // RNE
}
__device__ __forceinline__ float bf2f(unsigned short b) {
    return __uint_as_float(((unsigned)b) << 16);
}

// workspace layout (4-byte units)
#define WS_W1B   0
#define N_W1B    2048                  // 8192 B: [2][64 co][64 k] i8 signs
#define WS_W2P   (WS_W1B + N_W1B)
#define N_W2P    (9*128*64)
#define WS_W3P   (WS_W2P + N_W2P)
#define N_W3P    (9*256*128)
#define WS_WTF1  (WS_W3P + N_W3P)
#define N_WTF1   (256*4096)            // ushort signs [256][8192]
#define WS_WTF2  (WS_WTF1 + N_WTF1)
#define N_WTF2   (10*256)
#define WS_A1    (WS_WTF2 + N_WTF2)
#define N_A1     (1024*256*64)         // a1: [B][256px][64 fp32]; parts alias
#define WS_A2    (WS_A1 + N_A1)
#define N_A2     (1024*64*128)         // a2: [B][64px][256 ushort] (hi/lo bf16)
#define WS_A3    (WS_A2 + N_A2)
#define N_A3     (1024*16*256)         // a3: [B][16px][512 ushort]
#define WS_F1    (WS_A3 + N_A3)
#define N_F1     (1024*256)
#define WS_SCR   (WS_F1 + N_F1)

#define FC1_S    16

struct TernArgs {
    const float* w[6];
    int n[6];
};

// ---------------------------------------------------------------------------
// Stats pass 1: wi<5 -> sum|w|; wi==5 -> amax(x) -> ((int*)(scr+20))[0].
// ---------------------------------------------------------------------------
__global__ void tern_stats1(TernArgs ta, double* __restrict__ scr) {
    const int wi = blockIdx.y;
    const float* __restrict__ w = ta.w[wi];
    const int n = ta.n[wi];
    __shared__ double red[4];
    const int lane = threadIdx.x & 63, wv = threadIdx.x >> 6;
    if (wi == 5) {
        float m = 0.f;
        for (int i = blockIdx.x * blockDim.x + threadIdx.x; i < n;
             i += gridDim.x * blockDim.x)
            m = fmaxf(m, fabsf(w[i]));
        #pragma unroll
        for (int off = 32; off > 0; off >>= 1)
            m = fmaxf(m, __shfl_down(m, off, 64));
        if (lane == 0) red[wv] = (double)m;
        __syncthreads();
        if (threadIdx.x == 0) {
            float mm = (float)fmax(fmax(red[0], red[1]), fmax(red[2], red[3]));
            atomicMax((int*)(scr + 20), __float_as_int(mm));
        }
        return;
    }
    double s = 0.0;
    for (int i = blockIdx.x * blockDim.x + threadIdx.x; i < n;
         i += gridDim.x * blockDim.x)
        s += (double)fabsf(w[i]);
    #pragma unroll
    for (int off = 32; off > 0; off >>= 1) s += __shfl_down(s, off, 64);
    if (lane == 0) red[wv] = s;
    __syncthreads();
    if (threadIdx.x == 0)
        atomicAdd(scr + wi * 4, red[0] + red[1] + red[2] + red[3]);
}

__global__ void tern_stats2(TernArgs ta, double* __restrict__ scr) {
    const int wi = blockIdx.y;
    const float* __restrict__ w = ta.w[wi];
    const int n = ta.n[wi];
    const float delta = (float)(0.7 * scr[wi * 4] / (double)n);
    double ms = 0.0, cnt = 0.0;
    for (int i = blockIdx.x * blockDim.x + threadIdx.x; i < n;
         i += gridDim.x * blockDim.x) {
        float a = fabsf(w[i]);
        if (a > delta) { ms += (double)a; cnt += 1.0; }
    }
    #pragma unroll
    for (int off = 32; off > 0; off >>= 1) {
        ms += __shfl_down(ms, off, 64);
        cnt += __shfl_down(cnt, off, 64);
    }
    __shared__ double redm[4], redc[4];
    const int lane = threadIdx.x & 63, wv = threadIdx.x >> 6;
    if (lane == 0) { redm[wv] = ms; redc[wv] = cnt; }
    __syncthreads();
    if (threadIdx.x == 0) {
        atomicAdd(scr + wi * 4 + 1, redm[0] + redm[1] + redm[2] + redm[3]);
        atomicAdd(scr + wi * 4 + 2, redc[0] + redc[1] + redc[2] + redc[3]);
    }
}

// ---------------------------------------------------------------------------
// Fused writer (same as R12).
// ---------------------------------------------------------------------------
__global__ void tern_write_all(TernArgs ta, const double* __restrict__ scr,
                               signed char* __restrict__ w1b,
                               signed char* __restrict__ w2p8,
                               signed char* __restrict__ w3p8,
                               unsigned short* __restrict__ wtf1b,
                               float* __restrict__ wtf2) {
    const int wi = blockIdx.y;
    const float* __restrict__ w = ta.w[wi];
    const int n = ta.n[wi];
    const double* sc = scr + wi * 4;
    const float delta = (float)(0.7 * sc[0] / (double)n);
    const int i0 = blockIdx.x * blockDim.x + threadIdx.x;
    const int stride = gridDim.x * blockDim.x;

    if (wi == 0) {
        for (int i = i0; i < n; i += stride) {       // n = 1728 = 64*27
            const int co = i / 27;
            const int kp = i % 27;                    // ci*9 + tap
            float v = w[i];
            signed char s = (fabsf(v) > delta) ? (v > 0.0f ? 1 : -1) : 0;
            w1b[co * 64 + kp] = s;                    // BL, k = kp
            w1b[4096 + co * 64 + 32 + kp] = s;        // BH, k = 32+kp
        }
    } else if (wi == 4) {
        const double c = sc[2];
        const float alpha = (float)(sc[1] / (c > 1.0 ? c : 1.0));
        for (int i = i0; i < n; i += stride) {
            float v = w[i];
            wtf2[i] = (fabsf(v) > delta) ? (v > 0.0f ? alpha : -alpha) : 0.0f;
        }
    } else if (wi == 1 || wi == 2) {
        const int CIc = (wi == 1) ? 64 : 128;
        const int COc = (wi == 1) ? 128 : 256;
        signed char* dst = (wi == 1) ? w2p8 : w3p8;
        for (int i = i0; i < n; i += stride) {
            const int co = i / (CIc * 9);
            const int r = i % (CIc * 9);
            const int ci = r / 9, tap = r % 9;
            float v = w[i];
            signed char s = (fabsf(v) > delta) ? (v > 0.0f ? 1 : -1) : 0;
            dst[(tap * COc + co) * CIc + ci] = s;
        }
    } else {  // wi == 3: fc1 signs, hi and lo slots
        for (int i = i0; i < n; i += stride) {
            const int j = i >> 12;
            const int k = i & 4095;
            const int c = k >> 4, px = k & 15;
            float v = w[i];
            unsigned short s = (fabsf(v) > delta) ? (v > 0.0f ? 0x3f80 : 0xbf80) : 0;
            unsigned short* row = wtf1b + ((long)j << 13) + px * 512 + c;
            row[0] = s;
            row[256] = s;
        }
    }
}

// ---------------------------------------------------------------------------
// conv1 (unchanged from R12): i8 MFMA, no K-loop, block = 1 image.
// ---------------------------------------------------------------------------
__global__ __launch_bounds__(256) void conv1_i8(
        const float* __restrict__ x,
        const signed char* __restrict__ w1b,   // [2][64 co][64 k]
        const float* __restrict__ bias,
        const double* __restrict__ scr,        // w1 stats {sum, msum, count}
        const int* __restrict__ amax_x,
        int* __restrict__ amax_out,
        float* __restrict__ y) {
    constexpr int PL = 3472;                   // plane stride bytes
    __shared__ __align__(16) char X[2 * PL];
    __shared__ float redm[4];

    const int b = blockIdx.x;
    const int tid = threadIdx.x;
    const float S = 32512.0f / fmaxf(__int_as_float(*amax_x), 1e-30f);

    for (int i = tid; i < 2 * PL / 16; i += 256)
        ((int4*)X)[i] = make_int4(0, 0, 0, 0);
    __syncthreads();

    for (int i = tid; i < 768; i += 256) {
        const float4 v = ((const float4*)(x + (long)b * 3072))[i];
        const int e = i * 4;
        const int ci = e >> 10;
        const int rem = e & 1023;
        const int h = rem >> 5, w = rem & 31;
        const int base = ci * 1156 + (h + 1) * 34 + (w + 1);
        const float f[4] = {v.x, v.y, v.z, v.w};
        #pragma unroll
        for (int j = 0; j < 4; j++) {
            const int q = __float2int_rn(f[j] * S);
            const int ql = (q << 24) >> 24;
            const int qh = (q - ql) >> 8;
            X[base + j] = (char)ql;
            X[PL + base + j] = (char)qh;
        }
    }
    __syncthreads();

    const int lane = tid & 63;
    const int wid = tid >> 6;
    const int lm = lane & 15;
    const int kg = lane >> 4;

    const int poff = (kg >= 2) ? PL : 0;
    int cst[16];
    #pragma unroll
    for (int j = 0; j < 16; j++) {
        const int kp = (kg & 1) * 16 + j;
        cst[j] = (kp < 27)
                     ? ((kp / 9) * 1156 + ((kp % 9) / 3) * 34 + (kp % 9) % 3)
                     : 0;
    }

    i32x4 BL[4], BH[4];
    #pragma unroll
    for (int nt = 0; nt < 4; nt++) {
        const int co = nt * 16 + lm;
        BL[nt] = *(const i32x4*)(w1b + (long)co * 64 + kg * 16);
        BH[nt] = *(const i32x4*)(w1b + 4096 + (long)co * 64 + kg * 16);
    }

    const double c2 = scr[2];
    const float alpha = (float)(scr[1] / (c2 > 1.0 ? c2 : 1.0));
    const float dq = alpha / S;
    float tmax = 0.f;
    float* yb = y + (long)b * 256 * 64;

    for (int tt = 0; tt < 16; ++tt) {
        const int t = wid * 16 + tt;
        const int pp = t * 4 + (lm >> 2);
        const int sub = lm & 3;
        const int h = 2 * (pp >> 4) + (sub >> 1);
        const int w = 2 * (pp & 15) + (sub & 1);
        const int base = poff + h * 34 + w;
        unsigned d[4] = {0u, 0u, 0u, 0u};
        #pragma unroll
        for (int j = 0; j < 16; j++) {
            const unsigned byte = (unsigned char)X[base + cst[j]];
            d[j >> 2] |= byte << ((j & 3) * 8);
        }
        i32x4 Af;
        Af[0] = (int)d[0]; Af[1] = (int)d[1];
        Af[2] = (int)d[2]; Af[3] = (int)d[3];

        const int opp = t * 4 + kg;
        float* yr = yb + (long)opp * 64;
        #pragma unroll
        for (int nt = 0; nt < 4; nt++) {
            i32x4 aL = 0, aH = 0;
            aL = __builtin_amdgcn_mfma_i32_16x16x64_i8(Af, BL[nt], aL, 0, 0, 0);
            aH = __builtin_amdgcn_mfma_i32_16x16x64_i8(Af, BH[nt], aH, 0, 0, 0);
            const int s0 = aH[0] * 256 + aL[0];
            const int s1 = aH[1] * 256 + aL[1];
            const int s2 = aH[2] * 256 + aL[2];
            const int s3 = aH[3] * 256 + aL[3];
            int sm = s0 > s1 ? s0 : s1;
            const int sn = s2 > s3 ? s2 : s3;
            sm = sm > sn ? sm : sn;
            const int co = nt * 16 + lm;
            const float o = fmaxf(dq * (float)sm + bias[co], 0.f);
            tmax = fmaxf(tmax, o);
            yr[co] = o;
        }
    }

    #pragma unroll
    for (int off = 32; off > 0; off >>= 1)
        tmax = fmaxf(tmax, __shfl_down(tmax, off, 64));
    if (lane == 0) redm[wid] = tmax;
    __syncthreads();
    if (tid == 0) {
        float m = fmaxf(fmaxf(redm[0], redm[1]), fmaxf(redm[2], redm[3]));
        atomicMax(amax_out, __float_as_int(m));
    }
}

// ---------------------------------------------------------------------------
// int8 MFMA conv, round-13: 512 threads = 8 waves (WM x WN), per-wave tile
// MT=2 x NT=4 -> 64 acc VGPRs. __launch_bounds__(512,4) caps VGPR at 128
// -> 2 blocks/CU resident. B double-buffered; A loaded per-plane.
// ---------------------------------------------------------------------------
template <int CI, int HI, int CO, int HB, int WM, int WN, bool INF32>
__global__ __launch_bounds__(512, 4) void conv_i8(
        const void* __restrict__ xin,
        const signed char* __restrict__ wp,     // [9][CO][CI] int8 signs
        const float* __restrict__ bias,
        const double* __restrict__ scr,         // layer {_, msum, count}
        const int* __restrict__ amax_in,
        int* __restrict__ amax_out,             // nullptr if unused
        unsigned short* __restrict__ yout) {
    constexpr int CH8 = CI / 64;
    constexpr int NITER = 9 * CH8;
    constexpr int HR = HI / HB;
    constexpr int ROWS = HR + 2;
    constexpr int COLS = HI + 2;
    constexpr int NPIX = ROWS * COLS;
    constexpr int PSTR = NPIX * 64 + 32;    // bytes per g-plane
    constexpr int PO = HI / 2;
    constexpr int POR = HR / 2;
    constexpr int MT = 2, NT = 4;
    constexpr int TOT = ROWS * HI * (CI / 8);
    constexpr int NST = (TOT + 511) / 512;
    static_assert(WM * WN == 8, "8 waves");
    static_assert(WM * MT * 16 == HR * HI, "M covers slab pixels");
    static_assert(WN * NT * 16 == CO, "N covers all co");

    __shared__ __align__(16) char X[2 * CH8 * PSTR];
    __shared__ float redm[8];

    const int bimg = blockIdx.x / HB;
    const int hb = blockIdx.x % HB;
    const int tid = threadIdx.x;

    const float S = 32512.0f / fmaxf(__int_as_float(*amax_in), 1e-30f);

    // halo zero (borders only; disjoint from interior staging)
    constexpr int HALO = 2 * COLS + 2 * (ROWS - 2);
    for (int i = tid; i < HALO * 2 * CH8 * 4; i += 512) {
        const int u = i & 3;
        const int t = i >> 2;
        const int g = t % (2 * CH8);
        const int hp = t / (2 * CH8);
        int p;
        if (hp < COLS) p = hp;
        else if (hp < 2 * COLS) p = (ROWS - 1) * COLS + (hp - COLS);
        else {
            const int e = hp - 2 * COLS;
            p = (1 + (e >> 1)) * COLS + ((e & 1) ? (COLS - 1) : 0);
        }
        *(int4*)&X[g * PSTR + p * 64 + u * 16] = make_int4(0, 0, 0, 0);
    }

    // ---- staging phase 1: batch all global loads ----
    uint4 va[NST], vb[NST];
    bool val[NST];
    int pidx[NST], cbase[NST];
    #pragma unroll
    for (int s2 = 0; s2 < NST; s2++) {
        const int i = tid + s2 * 512;
        const bool inb = i < TOT;
        const int q8 = i % (CI / 8);
        const int t = i / (CI / 8);
        const int c = t % HI;
        const int r = t / HI;
        const int h = hb * HR + r - 1;
        val[s2] = inb && ((unsigned)h < (unsigned)HI);
        pidx[s2] = r * COLS + c + 1;
        cbase[s2] = q8 * 8;
        if (val[s2]) {
            if (INF32) {
                const float* pxr = (const float*)xin +
                    ((long)(bimg * HI + h) * HI + c) * CI + q8 * 8;
                va[s2] = *(const uint4*)(pxr);
                vb[s2] = *(const uint4*)(pxr + 4);
            } else {
                const unsigned short* pxr = (const unsigned short*)xin +
                    ((long)(bimg * HI + h) * HI + c) * (2 * CI);
                va[s2] = *(const uint4*)(pxr + q8 * 8);
                vb[s2] = *(const uint4*)(pxr + CI + q8 * 8);
            }
        }
    }
    // ---- staging phase 2: quantize + LDS store ----
    #pragma unroll
    for (int s2 = 0; s2 < NST; s2++) {
        if (!val[s2]) continue;
        float f[8];
        if (INF32) {
            const float* fa = (const float*)&va[s2];
            const float* fb = (const float*)&vb[s2];
            #pragma unroll
            for (int j = 0; j < 4; j++) { f[j] = fa[j]; f[4 + j] = fb[j]; }
        } else {
            const unsigned* hw = (const unsigned*)&va[s2];
            const unsigned* lw = (const unsigned*)&vb[s2];
            #pragma unroll
            for (int j = 0; j < 8; j++) {
                const unsigned hu = (j & 1) ? (hw[j >> 1] >> 16)
                                            : (hw[j >> 1] & 0xffffu);
                const unsigned lu = (j & 1) ? (lw[j >> 1] >> 16)
                                            : (lw[j >> 1] & 0xffffu);
                f[j] = __uint_as_float(hu << 16) + __uint_as_float(lu << 16);
            }
        }
        unsigned pl0 = 0, pl1 = 0, ph0 = 0, ph1 = 0;
        #pragma unroll
        for (int j = 0; j < 8; j++) {
            const int qi = (int)(f[j] * S + 0.5f);    // inputs >= 0 (post-relu)
            const int ql = (qi << 24) >> 24;
            const int qh = (qi - ql) >> 8;
            const int sh = (j & 3) * 8;
            if (j < 4) {
                pl0 |= (unsigned)(ql & 255) << sh;
                ph0 |= (unsigned)(qh & 255) << sh;
            } else {
                pl1 |= (unsigned)(ql & 255) << sh;
                ph1 |= (unsigned)(qh & 255) << sh;
            }
        }
        const int p = pidx[s2];
        const int ch = cbase[s2] >> 6;
        const int cc = cbase[s2] & 63;
        const int slot = ((cc >> 4) + (p >> 1)) & 3;
        const int base = p * 64 + slot * 16 + (cc & 15);
        *(uint2*)&X[ch * PSTR + base] = make_uint2(pl0, pl1);
        *(uint2*)&X[(CH8 + ch) * PSTR + base] = make_uint2(ph0, ph1);
    }
    __syncthreads();

    const int lane = tid & 63;
    const int wid = tid >> 6;
    const int wm = wid / WN;
    const int wn = wid % WN;
    const int lm = lane & 15;
    const int kg = lane >> 4;

    int pb[MT];
    #pragma unroll
    for (int mt = 0; mt < MT; mt++) {
        const int m = (wm * MT + mt) * 16 + lm;
        const int pp = m >> 2, sub = m & 3;
        const int lph = pp / PO, lpw = pp % PO;
        const int h = 2 * lph + (sub >> 1);
        const int w = 2 * lpw + (sub & 1);
        pb[mt] = h * COLS + w;
    }
    const signed char* bp[NT];
    #pragma unroll
    for (int nt = 0; nt < NT; nt++) {
        const int co = (wn * NT + nt) * 16 + lm;
        bp[nt] = wp + (long)co * CI + kg * 16;
    }

    i32x4 accL[MT][NT], accH[MT][NT];
    #pragma unroll
    for (int mt = 0; mt < MT; mt++)
        #pragma unroll
        for (int nt = 0; nt < NT; nt++) { accL[mt][nt] = 0; accH[mt][nt] = 0; }

    i32x4 Bb[2][NT];
    #pragma unroll
    for (int nt = 0; nt < NT; nt++) Bb[0][nt] = *(const i32x4*)(bp[nt]);

    #pragma unroll 2
    for (int it = 0; it < NITER; ++it) {
        const int cur = it & 1, nxt = cur ^ 1;
        if (it + 1 < NITER) {
            const int it1 = it + 1;
            const int tap = it1 / CH8, ch1 = it1 % CH8;
            const int woff = tap * CO * CI + ch1 * 64;
            #pragma unroll
            for (int nt = 0; nt < NT; nt++)
                Bb[nxt][nt] = *(const i32x4*)(bp[nt] + woff);
        }
        const int tap = it / CH8, ch = it % CH8;
        const int dtap = (tap / 3) * COLS + (tap % 3);
        int ao[MT];
        #pragma unroll
        for (int mt = 0; mt < MT; mt++) {
            const int p = pb[mt] + dtap;
            ao[mt] = p * 64 + (((kg + (p >> 1)) & 3) << 4);
        }
        {
            i32x4 Af[MT];
            #pragma unroll
            for (int mt = 0; mt < MT; mt++)
                Af[mt] = *(const i32x4*)&X[ch * PSTR + ao[mt]];
            #pragma unroll
            for (int mt = 0; mt < MT; mt++)
                #pragma unroll
                for (int nt = 0; nt < NT; nt++)
                    accL[mt][nt] = __builtin_amdgcn_mfma_i32_16x16x64_i8(
                        Af[mt], Bb[cur][nt], accL[mt][nt], 0, 0, 0);
        }
        {
            i32x4 Af[MT];
            #pragma unroll
            for (int mt = 0; mt < MT; mt++)
                Af[mt] = *(const i32x4*)&X[(CH8 + ch) * PSTR + ao[mt]];
            #pragma unroll
            for (int mt = 0; mt < MT; mt++)
                #pragma unroll
                for (int nt = 0; nt < NT; nt++)
                    accH[mt][nt] = __builtin_amdgcn_mfma_i32_16x16x64_i8(
                        Af[mt], Bb[cur][nt], accH[mt][nt], 0, 0, 0);
        }
    }

    // epilogue: sum = 256*accH + accL (exact i32); pool in int; dq + bias + relu
    const double c2 = scr[2];
    const float alpha = (float)(scr[1] / (c2 > 1.0 ? c2 : 1.0));
    const float dq = alpha / S;
    float tmax = 0.f;
    #pragma unroll
    for (int mt = 0; mt < MT; mt++) {
        const int pp = (wm * MT + mt) * 4 + kg;
        const int lph = pp / PO, lpw = pp % PO;
        const int gpp = (hb * POR + lph) * PO + lpw;
        unsigned short* yr = yout + ((long)bimg * (PO * PO) + gpp) * (2 * CO);
        #pragma unroll
        for (int nt = 0; nt < NT; nt++) {
            const int co = (wn * NT + nt) * 16 + lm;
            const i32x4 aL = accL[mt][nt], aH = accH[mt][nt];
            int s0 = aH[0] * 256 + aL[0];
            int s1 = aH[1] * 256 + aL[1];
            int s2 = aH[2] * 256 + aL[2];
            int s3 = aH[3] * 256 + aL[3];
            int sm = s0 > s1 ? s0 : s1;
            int sn = s2 > s3 ? s2 : s3;
            sm = sm > sn ? sm : sn;
            float o = fmaxf(dq * (float)sm + bias[co], 0.f);
            tmax = fmaxf(tmax, o);
            unsigned short hi = f2bf(o);
            unsigned short lo = f2bf(o - bf2f(hi));
            yr[co] = hi;
            yr[CO + co] = lo;
        }
    }
    if (amax_out) {
        #pragma unroll
        for (int off = 32; off > 0; off >>= 1)
            tmax = fmaxf(tmax, __shfl_down(tmax, off, 64));
        if (lane == 0) redm[wid] = tmax;
        __syncthreads();
        if (tid == 0) {
            float m = 0.f;
            #pragma unroll
            for (int i = 0; i < 8; i++) m = fmaxf(m, redm[i]);
            atomicMax(amax_out, __float_as_int(m));
        }
    }
}

// ---------------------------------------------------------------------------
// fc1 MFMA (bf16): K=8192 hi/lo slots, split-K, reg-pipelined.
// ---------------------------------------------------------------------------
template <int S>
__global__ __launch_bounds__(256) void fc1_mfma(
        const unsigned short* __restrict__ A,
        const unsigned short* __restrict__ Bw,
        float* __restrict__ parts) {
    constexpr int KCH = 8192 / S;
    constexpr int NSTEP = KCH / 32;
    const int m0 = blockIdx.x * 128;
    const int n0 = blockIdx.y * 128;
    const int s = blockIdx.z;
    const int tid = threadIdx.x;
    const int lane = tid & 63, wid = tid >> 6;
    const int wm = wid >> 1, wn = wid & 1;
    const int lm = lane & 15, kg = lane >> 4;

    const long k0 = (long)s * KCH + kg * 8;
    const unsigned short* ap[4];
    const unsigned short* bp[4];
    #pragma unroll
    for (int t = 0; t < 4; t++) {
        ap[t] = A + (long)(m0 + wm * 64 + t * 16 + lm) * 8192 + k0;
        bp[t] = Bw + (long)(n0 + wn * 64 + t * 16 + lm) * 8192 + k0;
    }

    f32x4 acc[4][4] = {};
    short8 Ab[2][4], Bb[2][4];
    #pragma unroll
    for (int t = 0; t < 4; t++) {
        Ab[0][t] = *(const short8*)(ap[t]);
        Bb[0][t] = *(const short8*)(bp[t]);
    }

    #pragma unroll 2
    for (int st = 0; st < NSTEP; ++st) {
        const int cur = st & 1, nxt = cur ^ 1;
        if (st + 1 < NSTEP) {
            const int off = (st + 1) * 32;
            #pragma unroll
            for (int t = 0; t < 4; t++) {
                Ab[nxt][t] = *(const short8*)(ap[t] + off);
                Bb[nxt][t] = *(const short8*)(bp[t] + off);
            }
        }
        #pragma unroll
        for (int mt = 0; mt < 4; mt++)
            #pragma unroll
            for (int nt = 0; nt < 4; nt++)
                acc[mt][nt] = __builtin_amdgcn_mfma_f32_16x16x32_bf16(
                    Ab[cur][mt], Bb[cur][nt], acc[mt][nt], 0, 0, 0);
    }

    #pragma unroll
    for (int mt = 0; mt < 4; mt++) {
        #pragma unroll
        for (int r = 0; r < 4; r++) {
            const int b = m0 + wm * 64 + mt * 16 + kg * 4 + r;
            #pragma unroll
            for (int nt = 0; nt < 4; nt++) {
                const int j = n0 + wn * 64 + nt * 16 + lm;
                parts[((long)s * 1024 + b) * 256 + j] = acc[mt][nt][r];
            }
        }
    }
}

template <int S>
__global__ void fc1_reduce(const float* __restrict__ parts,
                           const double* __restrict__ scr,
                           const float* __restrict__ bias,
                           float* __restrict__ f1) {
    const int idx = blockIdx.x * blockDim.x + threadIdx.x;  // < 262144
    const int j = idx & 255;
    float s = 0.f;
    #pragma unroll
    for (int p = 0; p < S; p++) s += parts[(long)p * 262144 + idx];
    const double c2 = scr[2];
    const float alpha = (float)(scr[1] / (c2 > 1.0 ? c2 : 1.0));
    f1[idx] = fmaxf(alpha * s + bias[j], 0.f);
}

__global__ void fc2_kernel(const float* __restrict__ a,
                           const float* __restrict__ wt,
                           const float* __restrict__ bias,
                           float* __restrict__ out, int B) {
    const int idx = blockIdx.x * blockDim.x + threadIdx.x;
    if (idx >= B * 10) return;
    const int k = idx % 10;
    const int b = idx / 10;
    const float* ar = a + (long)b * 256;
    const float* wr = wt + (long)k * 256;
    float acc = 0.f;
    #pragma unroll 4
    for (int i = 0; i < 256; i++) acc += ar[i] * wr[i];
    out[idx] = acc + bias[k];
}

extern "C" void kernel_launch(void* const* d_in, const int* in_sizes, int n_in,
                              void* d_out, int out_size, void* d_ws, size_t ws_size,
                              hipStream_t stream) {
    const float* x   = (const float*)d_in[0];
    const float* w1  = (const float*)d_in[1];
    const float* b1  = (const float*)d_in[2];
    const float* w2  = (const float*)d_in[3];
    const float* b2  = (const float*)d_in[4];
    const float* w3  = (const float*)d_in[5];
    const float* b3  = (const float*)d_in[6];
    const float* wf1 = (const float*)d_in[7];
    const float* bf1 = (const float*)d_in[8];
    const float* wf2 = (const float*)d_in[9];
    const float* bf2 = (const float*)d_in[10];
    float* out = (float*)d_out;
    float* ws = (float*)d_ws;

    const int B = 1024;

    signed char*    w1b   = (signed char*)(ws + WS_W1B);
    signed char*    w2p8  = (signed char*)(ws + WS_W2P);
    signed char*    w3p8  = (signed char*)(ws + WS_W3P);
    unsigned short* wtf1b = (unsigned short*)(ws + WS_WTF1);
    float*          wtf2  = ws + WS_WTF2;
    float*          a1f   = ws + WS_A1;
    unsigned short* a2p   = (unsigned short*)(ws + WS_A2);
    unsigned short* a3p   = (unsigned short*)(ws + WS_A3);
    float*          f1    = ws + WS_F1;
    double*         scr   = (double*)(ws + WS_SCR);
    int*            iscr  = (int*)(scr + 20);
    int*            amaxx = iscr;           // amax(x)
    int*            amax1 = iscr + 1;       // amax(a1)
    int*            amax2 = iscr + 2;       // amax(a2)
    float*          parts = ws + WS_A1;     // alias: a1 dead after conv2

    hipMemsetAsync(scr, 0, 22 * sizeof(double), stream);
    hipMemsetAsync(w1b, 0, 8192, stream);   // BL/BH zero padding

    TernArgs ta;
    ta.w[0] = w1;  ta.n[0] = 64 * 27;
    ta.w[1] = w2;  ta.n[1] = 128 * 64 * 9;
    ta.w[2] = w3;  ta.n[2] = 256 * 128 * 9;
    ta.w[3] = wf1; ta.n[3] = 256 * 4096;
    ta.w[4] = wf2; ta.n[4] = 10 * 256;
    ta.w[5] = x;   ta.n[5] = 1024 * 3 * 32 * 32;   // amax(x)

    hipLaunchKernelGGL(tern_stats1, dim3(128, 6), dim3(256), 0, stream, ta, scr);
    hipLaunchKernelGGL(tern_stats2, dim3(128, 5), dim3(256), 0, stream, ta, scr);
    hipLaunchKernelGGL(tern_write_all, dim3(128, 5), dim3(256), 0, stream,
                       ta, scr, w1b, w2p8, w3p8, wtf1b, wtf2);

    // conv1: i8 MFMA, 1 block per image -> a1 fp32 rows + amax1
    hipLaunchKernelGGL(conv1_i8, dim3(B), dim3(256), 0, stream,
                       x, w1b, b1, scr + 0, amaxx, amax1, a1f);

    // conv2: CI=64, HI=16, CO=128, HB=2, WM=4, WN=2, fp32 in -> 2048 x 512
    hipLaunchKernelGGL((conv_i8<64, 16, 128, 2, 4, 2, true>), dim3(B * 2),
                       dim3(512), 0, stream, a1f, w2p8, b2, scr + 4, amax1,
                       amax2, a2p);

    // conv3: CI=128, HI=8, CO=256, HB=1, WM=2, WN=4 -> 1024 x 512
    hipLaunchKernelGGL((conv_i8<128, 8, 256, 1, 2, 4, false>), dim3(B),
                       dim3(512), 0, stream, a2p, w3p8, b3, scr + 8, amax2,
                       (int*)nullptr, a3p);

    // fc1: MFMA split-K + reduce(alpha+bias+relu)
    hipLaunchKernelGGL((fc1_mfma<FC1_S>), dim3(8, 2, FC1_S), dim3(256), 0, stream,
                       a3p, wtf1b, parts);
    hipLaunchKernelGGL((fc1_reduce<FC1_S>), dim3(1024), dim3(256), 0, stream,
                       parts, scr + 12, bf1, f1);

    // fc2
    hipLaunchKernelGGL(fc2_kernel, dim3((B * 10 + 255) / 256), dim3(256), 0,
                       stream, f1, wtf2, bf2, out, B);
}

// Round 14
// 285.515 us; speedup vs baseline: 1.1582x; 1.1582x over previous
//
#include <hip/hip_runtime.h>
#include <hip/hip_bf16.h>

// ---------------------------------------------------------------------------
// TernaryCIFAR10Net on MI355X — Round 14:
//   Revert conv_i8 to R12's MT=4 x NT=4, 256-thread shape (R13's MT=2
//   regressed: 16-MFMA windows can't cover B latency). Occupancy via
//   __launch_bounds__(256,2): acc lives in 128 AGPRs, staging re-merged to
//   a streaming loop so VGPRs fit in 128 -> 2 blocks/CU.
//   fc1_reduce + fc2 fused into one per-image kernel.
//   conv1 (i8 MFMA K-free), fc1_mfma, ternarize unchanged from R12.
// ---------------------------------------------------------------------------

typedef __attribute__((ext_vector_type(8))) short short8;
typedef __attribute__((ext_vector_type(4))) float f32x4;
typedef __attribute__((ext_vector_type(4))) int i32x4;

__device__ __forceinline__ unsigned short f2bf(float x) {
    unsigned u = __float_as_uint(x);
    return (unsigned short)((u + 0x7fffu + ((u >> 16) & 1u)) >> 16);  // RNE
}
__device__ __forceinline__ float bf2f(unsigned short b) {
    return __uint_as_float(((unsigned)b) << 16);
}

// workspace layout (4-byte units)
#define WS_W1B   0
#define N_W1B    2048                  // 8192 B: [2][64 co][64 k] i8 signs
#define WS_W2P   (WS_W1B + N_W1B)
#define N_W2P    (9*128*64)
#define WS_W3P   (WS_W2P + N_W2P)
#define N_W3P    (9*256*128)
#define WS_WTF1  (WS_W3P + N_W3P)
#define N_WTF1   (256*4096)            // ushort signs [256][8192]
#define WS_WTF2  (WS_WTF1 + N_WTF1)
#define N_WTF2   (10*256)
#define WS_A1    (WS_WTF2 + N_WTF2)
#define N_A1     (1024*256*64)         // a1: [B][256px][64 fp32]; parts alias
#define WS_A2    (WS_A1 + N_A1)
#define N_A2     (1024*64*128)         // a2: [B][64px][256 ushort] (hi/lo bf16)
#define WS_A3    (WS_A2 + N_A2)
#define N_A3     (1024*16*256)         // a3: [B][16px][512 ushort]
#define WS_F1    (WS_A3 + N_A3)
#define N_F1     (1024*256)
#define WS_SCR   (WS_F1 + N_F1)

#define FC1_S    16

struct TernArgs {
    const float* w[6];
    int n[6];
};

// ---------------------------------------------------------------------------
// Stats pass 1: wi<5 -> sum|w|; wi==5 -> amax(x) -> ((int*)(scr+20))[0].
// ---------------------------------------------------------------------------
__global__ void tern_stats1(TernArgs ta, double* __restrict__ scr) {
    const int wi = blockIdx.y;
    const float* __restrict__ w = ta.w[wi];
    const int n = ta.n[wi];
    __shared__ double red[4];
    const int lane = threadIdx.x & 63, wv = threadIdx.x >> 6;
    if (wi == 5) {
        float m = 0.f;
        for (int i = blockIdx.x * blockDim.x + threadIdx.x; i < n;
             i += gridDim.x * blockDim.x)
            m = fmaxf(m, fabsf(w[i]));
        #pragma unroll
        for (int off = 32; off > 0; off >>= 1)
            m = fmaxf(m, __shfl_down(m, off, 64));
        if (lane == 0) red[wv] = (double)m;
        __syncthreads();
        if (threadIdx.x == 0) {
            float mm = (float)fmax(fmax(red[0], red[1]), fmax(red[2], red[3]));
            atomicMax((int*)(scr + 20), __float_as_int(mm));
        }
        return;
    }
    double s = 0.0;
    for (int i = blockIdx.x * blockDim.x + threadIdx.x; i < n;
         i += gridDim.x * blockDim.x)
        s += (double)fabsf(w[i]);
    #pragma unroll
    for (int off = 32; off > 0; off >>= 1) s += __shfl_down(s, off, 64);
    if (lane == 0) red[wv] = s;
    __syncthreads();
    if (threadIdx.x == 0)
        atomicAdd(scr + wi * 4, red[0] + red[1] + red[2] + red[3]);
}

__global__ void tern_stats2(TernArgs ta, double* __restrict__ scr) {
    const int wi = blockIdx.y;
    const float* __restrict__ w = ta.w[wi];
    const int n = ta.n[wi];
    const float delta = (float)(0.7 * scr[wi * 4] / (double)n);
    double ms = 0.0, cnt = 0.0;
    for (int i = blockIdx.x * blockDim.x + threadIdx.x; i < n;
         i += gridDim.x * blockDim.x) {
        float a = fabsf(w[i]);
        if (a > delta) { ms += (double)a; cnt += 1.0; }
    }
    #pragma unroll
    for (int off = 32; off > 0; off >>= 1) {
        ms += __shfl_down(ms, off, 64);
        cnt += __shfl_down(cnt, off, 64);
    }
    __shared__ double redm[4], redc[4];
    const int lane = threadIdx.x & 63, wv = threadIdx.x >> 6;
    if (lane == 0) { redm[wv] = ms; redc[wv] = cnt; }
    __syncthreads();
    if (threadIdx.x == 0) {
        atomicAdd(scr + wi * 4 + 1, redm[0] + redm[1] + redm[2] + redm[3]);
        atomicAdd(scr + wi * 4 + 2, redc[0] + redc[1] + redc[2] + redc[3]);
    }
}

// ---------------------------------------------------------------------------
// Fused writer (same as R12).
// ---------------------------------------------------------------------------
__global__ void tern_write_all(TernArgs ta, const double* __restrict__ scr,
                               signed char* __restrict__ w1b,
                               signed char* __restrict__ w2p8,
                               signed char* __restrict__ w3p8,
                               unsigned short* __restrict__ wtf1b,
                               float* __restrict__ wtf2) {
    const int wi = blockIdx.y;
    const float* __restrict__ w = ta.w[wi];
    const int n = ta.n[wi];
    const double* sc = scr + wi * 4;
    const float delta = (float)(0.7 * sc[0] / (double)n);
    const int i0 = blockIdx.x * blockDim.x + threadIdx.x;
    const int stride = gridDim.x * blockDim.x;

    if (wi == 0) {
        for (int i = i0; i < n; i += stride) {       // n = 1728 = 64*27
            const int co = i / 27;
            const int kp = i % 27;                    // ci*9 + tap
            float v = w[i];
            signed char s = (fabsf(v) > delta) ? (v > 0.0f ? 1 : -1) : 0;
            w1b[co * 64 + kp] = s;                    // BL, k = kp
            w1b[4096 + co * 64 + 32 + kp] = s;        // BH, k = 32+kp
        }
    } else if (wi == 4) {
        const double c = sc[2];
        const float alpha = (float)(sc[1] / (c > 1.0 ? c : 1.0));
        for (int i = i0; i < n; i += stride) {
            float v = w[i];
            wtf2[i] = (fabsf(v) > delta) ? (v > 0.0f ? alpha : -alpha) : 0.0f;
        }
    } else if (wi == 1 || wi == 2) {
        const int CIc = (wi == 1) ? 64 : 128;
        const int COc = (wi == 1) ? 128 : 256;
        signed char* dst = (wi == 1) ? w2p8 : w3p8;
        for (int i = i0; i < n; i += stride) {
            const int co = i / (CIc * 9);
            const int r = i % (CIc * 9);
            const int ci = r / 9, tap = r % 9;
            float v = w[i];
            signed char s = (fabsf(v) > delta) ? (v > 0.0f ? 1 : -1) : 0;
            dst[(tap * COc + co) * CIc + ci] = s;
        }
    } else {  // wi == 3: fc1 signs, hi and lo slots
        for (int i = i0; i < n; i += stride) {
            const int j = i >> 12;
            const int k = i & 4095;
            const int c = k >> 4, px = k & 15;
            float v = w[i];
            unsigned short s = (fabsf(v) > delta) ? (v > 0.0f ? 0x3f80 : 0xbf80) : 0;
            unsigned short* row = wtf1b + ((long)j << 13) + px * 512 + c;
            row[0] = s;
            row[256] = s;
        }
    }
}

// ---------------------------------------------------------------------------
// conv1 (unchanged from R12): i8 MFMA, no K-loop, block = 1 image.
// ---------------------------------------------------------------------------
__global__ __launch_bounds__(256) void conv1_i8(
        const float* __restrict__ x,
        const signed char* __restrict__ w1b,   // [2][64 co][64 k]
        const float* __restrict__ bias,
        const double* __restrict__ scr,        // w1 stats {sum, msum, count}
        const int* __restrict__ amax_x,
        int* __restrict__ amax_out,
        float* __restrict__ y) {
    constexpr int PL = 3472;                   // plane stride bytes
    __shared__ __align__(16) char X[2 * PL];
    __shared__ float redm[4];

    const int b = blockIdx.x;
    const int tid = threadIdx.x;
    const float S = 32512.0f / fmaxf(__int_as_float(*amax_x), 1e-30f);

    for (int i = tid; i < 2 * PL / 16; i += 256)
        ((int4*)X)[i] = make_int4(0, 0, 0, 0);
    __syncthreads();

    for (int i = tid; i < 768; i += 256) {
        const float4 v = ((const float4*)(x + (long)b * 3072))[i];
        const int e = i * 4;
        const int ci = e >> 10;
        const int rem = e & 1023;
        const int h = rem >> 5, w = rem & 31;
        const int base = ci * 1156 + (h + 1) * 34 + (w + 1);
        const float f[4] = {v.x, v.y, v.z, v.w};
        #pragma unroll
        for (int j = 0; j < 4; j++) {
            const int q = __float2int_rn(f[j] * S);
            const int ql = (q << 24) >> 24;
            const int qh = (q - ql) >> 8;
            X[base + j] = (char)ql;
            X[PL + base + j] = (char)qh;
        }
    }
    __syncthreads();

    const int lane = tid & 63;
    const int wid = tid >> 6;
    const int lm = lane & 15;
    const int kg = lane >> 4;

    const int poff = (kg >= 2) ? PL : 0;
    int cst[16];
    #pragma unroll
    for (int j = 0; j < 16; j++) {
        const int kp = (kg & 1) * 16 + j;
        cst[j] = (kp < 27)
                     ? ((kp / 9) * 1156 + ((kp % 9) / 3) * 34 + (kp % 9) % 3)
                     : 0;
    }

    i32x4 BL[4], BH[4];
    #pragma unroll
    for (int nt = 0; nt < 4; nt++) {
        const int co = nt * 16 + lm;
        BL[nt] = *(const i32x4*)(w1b + (long)co * 64 + kg * 16);
        BH[nt] = *(const i32x4*)(w1b + 4096 + (long)co * 64 + kg * 16);
    }

    const double c2 = scr[2];
    const float alpha = (float)(scr[1] / (c2 > 1.0 ? c2 : 1.0));
    const float dq = alpha / S;
    float tmax = 0.f;
    float* yb = y + (long)b * 256 * 64;

    for (int tt = 0; tt < 16; ++tt) {
        const int t = wid * 16 + tt;
        const int pp = t * 4 + (lm >> 2);
        const int sub = lm & 3;
        const int h = 2 * (pp >> 4) + (sub >> 1);
        const int w = 2 * (pp & 15) + (sub & 1);
        const int base = poff + h * 34 + w;
        unsigned d[4] = {0u, 0u, 0u, 0u};
        #pragma unroll
        for (int j = 0; j < 16; j++) {
            const unsigned byte = (unsigned char)X[base + cst[j]];
            d[j >> 2] |= byte << ((j & 3) * 8);
        }
        i32x4 Af;
        Af[0] = (int)d[0]; Af[1] = (int)d[1];
        Af[2] = (int)d[2]; Af[3] = (int)d[3];

        const int opp = t * 4 + kg;
        float* yr = yb + (long)opp * 64;
        #pragma unroll
        for (int nt = 0; nt < 4; nt++) {
            i32x4 aL = 0, aH = 0;
            aL = __builtin_amdgcn_mfma_i32_16x16x64_i8(Af, BL[nt], aL, 0, 0, 0);
            aH = __builtin_amdgcn_mfma_i32_16x16x64_i8(Af, BH[nt], aH, 0, 0, 0);
            const int s0 = aH[0] * 256 + aL[0];
            const int s1 = aH[1] * 256 + aL[1];
            const int s2 = aH[2] * 256 + aL[2];
            const int s3 = aH[3] * 256 + aL[3];
            int sm = s0 > s1 ? s0 : s1;
            const int sn = s2 > s3 ? s2 : s3;
            sm = sm > sn ? sm : sn;
            const int co = nt * 16 + lm;
            const float o = fmaxf(dq * (float)sm + bias[co], 0.f);
            tmax = fmaxf(tmax, o);
            yr[co] = o;
        }
    }

    #pragma unroll
    for (int off = 32; off > 0; off >>= 1)
        tmax = fmaxf(tmax, __shfl_down(tmax, off, 64));
    if (lane == 0) redm[wid] = tmax;
    __syncthreads();
    if (tid == 0) {
        float m = fmaxf(fmaxf(redm[0], redm[1]), fmaxf(redm[2], redm[3]));
        atomicMax(amax_out, __float_as_int(m));
    }
}

// ---------------------------------------------------------------------------
// int8 MFMA conv, round-14: R12 shape (256 thr, 4 waves, MT=4 x NT=4) with
// __launch_bounds__(256,2): acc in 128 AGPRs, streaming staging keeps VGPRs
// <=128 -> 2 blocks/CU. B double-buffered; A per-plane batched ds_reads.
// ---------------------------------------------------------------------------
template <int CI, int HI, int CO, int HB, int WM, int WN, bool INF32>
__global__ __launch_bounds__(256, 2) void conv_i8(
        const void* __restrict__ xin,
        const signed char* __restrict__ wp,     // [9][CO][CI] int8 signs
        const float* __restrict__ bias,
        const double* __restrict__ scr,         // layer {_, msum, count}
        const int* __restrict__ amax_in,
        int* __restrict__ amax_out,             // nullptr if unused
        unsigned short* __restrict__ yout) {
    constexpr int CH8 = CI / 64;
    constexpr int NITER = 9 * CH8;
    constexpr int HR = HI / HB;
    constexpr int ROWS = HR + 2;
    constexpr int COLS = HI + 2;
    constexpr int NPIX = ROWS * COLS;
    constexpr int PSTR = NPIX * 64 + 32;    // bytes per g-plane
    constexpr int PO = HI / 2;
    constexpr int POR = HR / 2;
    constexpr int MT = 4, NT = 4;
    static_assert(WM * WN == 4, "4 waves");
    static_assert(WM * 64 == HR * HI, "M covers slab pixels");
    static_assert(WN * 64 == CO, "N covers all co");

    __shared__ __align__(16) char X[2 * CH8 * PSTR];
    __shared__ float redm[4];

    const int bimg = blockIdx.x / HB;
    const int hb = blockIdx.x % HB;
    const int tid = threadIdx.x;

    const float S = 32512.0f / fmaxf(__int_as_float(*amax_in), 1e-30f);

    // halo zero (borders only; disjoint from interior staging)
    constexpr int HALO = 2 * COLS + 2 * (ROWS - 2);
    for (int i = tid; i < HALO * 2 * CH8 * 4; i += 256) {
        const int u = i & 3;
        const int t = i >> 2;
        const int g = t % (2 * CH8);
        const int hp = t / (2 * CH8);
        int p;
        if (hp < COLS) p = hp;
        else if (hp < 2 * COLS) p = (ROWS - 1) * COLS + (hp - COLS);
        else {
            const int e = hp - 2 * COLS;
            p = (1 + (e >> 1)) * COLS + ((e & 1) ? (COLS - 1) : 0);
        }
        *(int4*)&X[g * PSTR + p * 64 + u * 16] = make_int4(0, 0, 0, 0);
    }

    // streaming staging: load -> quantize -> LDS store (low reg pressure;
    // latency covered by the 2nd resident block's K-loop)
    for (int i = tid; i < ROWS * HI * (CI / 8); i += 256) {
        const int q8 = i % (CI / 8);
        const int t = i / (CI / 8);
        const int c = t % HI;
        const int r = t / HI;
        const int h = hb * HR + r - 1;
        if ((unsigned)h >= (unsigned)HI) continue;
        float f[8];
        if (INF32) {
            const float* pxr = (const float*)xin +
                ((long)(bimg * HI + h) * HI + c) * CI + q8 * 8;
            const float4 va = *(const float4*)(pxr);
            const float4 vb = *(const float4*)(pxr + 4);
            f[0] = va.x; f[1] = va.y; f[2] = va.z; f[3] = va.w;
            f[4] = vb.x; f[5] = vb.y; f[6] = vb.z; f[7] = vb.w;
        } else {
            const unsigned short* pxr = (const unsigned short*)xin +
                ((long)(bimg * HI + h) * HI + c) * (2 * CI);
            const uint4 vh = *(const uint4*)(pxr + q8 * 8);
            const uint4 vl = *(const uint4*)(pxr + CI + q8 * 8);
            const unsigned* hw = (const unsigned*)&vh;
            const unsigned* lw = (const unsigned*)&vl;
            #pragma unroll
            for (int j = 0; j < 8; j++) {
                const unsigned hu = (j & 1) ? (hw[j >> 1] >> 16)
                                            : (hw[j >> 1] & 0xffffu);
                const unsigned lu = (j & 1) ? (lw[j >> 1] >> 16)
                                            : (lw[j >> 1] & 0xffffu);
                f[j] = __uint_as_float(hu << 16) + __uint_as_float(lu << 16);
            }
        }
        unsigned pl0 = 0, pl1 = 0, ph0 = 0, ph1 = 0;
        #pragma unroll
        for (int j = 0; j < 8; j++) {
            const int qi = (int)(f[j] * S + 0.5f);    // inputs >= 0 (post-relu)
            const int ql = (qi << 24) >> 24;
            const int qh = (qi - ql) >> 8;
            const int sh = (j & 3) * 8;
            if (j < 4) {
                pl0 |= (unsigned)(ql & 255) << sh;
                ph0 |= (unsigned)(qh & 255) << sh;
            } else {
                pl1 |= (unsigned)(ql & 255) << sh;
                ph1 |= (unsigned)(qh & 255) << sh;
            }
        }
        const int p = r * COLS + c + 1;
        const int ch = q8 >> 3;                  // c8 = q8*8; ch = c8/64
        const int cc = (q8 * 8) & 63;
        const int slot = ((cc >> 4) + (p >> 1)) & 3;
        const int base = p * 64 + slot * 16 + (cc & 15);
        *(uint2*)&X[ch * PSTR + base] = make_uint2(pl0, pl1);
        *(uint2*)&X[(CH8 + ch) * PSTR + base] = make_uint2(ph0, ph1);
    }
    __syncthreads();

    const int lane = tid & 63;
    const int wid = tid >> 6;
    const int wm = (WM == 1) ? 0 : (wid >> 1);
    const int wn = (WM == 1) ? wid : (wid & 1);
    const int lm = lane & 15;
    const int kg = lane >> 4;

    int pb[MT];
    #pragma unroll
    for (int mt = 0; mt < MT; mt++) {
        const int m = (wm * MT + mt) * 16 + lm;
        const int pp = m >> 2, sub = m & 3;
        const int lph = pp / PO, lpw = pp % PO;
        const int h = 2 * lph + (sub >> 1);
        const int w = 2 * lpw + (sub & 1);
        pb[mt] = h * COLS + w;
    }
    const signed char* bp[NT];
    #pragma unroll
    for (int nt = 0; nt < NT; nt++) {
        const int co = (wn * NT + nt) * 16 + lm;
        bp[nt] = wp + (long)co * CI + kg * 16;
    }

    i32x4 accL[MT][NT], accH[MT][NT];
    #pragma unroll
    for (int mt = 0; mt < MT; mt++)
        #pragma unroll
        for (int nt = 0; nt < NT; nt++) { accL[mt][nt] = 0; accH[mt][nt] = 0; }

    i32x4 Bb[2][NT];
    #pragma unroll
    for (int nt = 0; nt < NT; nt++) Bb[0][nt] = *(const i32x4*)(bp[nt]);

    #pragma unroll 2
    for (int it = 0; it < NITER; ++it) {
        const int cur = it & 1, nxt = cur ^ 1;
        if (it + 1 < NITER) {
            const int it1 = it + 1;
            const int tap = it1 / CH8, ch1 = it1 % CH8;
            const int woff = tap * CO * CI + ch1 * 64;
            #pragma unroll
            for (int nt = 0; nt < NT; nt++)
                Bb[nxt][nt] = *(const i32x4*)(bp[nt] + woff);
        }
        const int tap = it / CH8, ch = it % CH8;
        const int dtap = (tap / 3) * COLS + (tap % 3);
        int ao[MT];
        #pragma unroll
        for (int mt = 0; mt < MT; mt++) {
            const int p = pb[mt] + dtap;
            ao[mt] = p * 64 + (((kg + (p >> 1)) & 3) << 4);
        }
        {
            i32x4 Af[MT];
            #pragma unroll
            for (int mt = 0; mt < MT; mt++)
                Af[mt] = *(const i32x4*)&X[ch * PSTR + ao[mt]];
            #pragma unroll
            for (int mt = 0; mt < MT; mt++)
                #pragma unroll
                for (int nt = 0; nt < NT; nt++)
                    accL[mt][nt] = __builtin_amdgcn_mfma_i32_16x16x64_i8(
                        Af[mt], Bb[cur][nt], accL[mt][nt], 0, 0, 0);
        }
        {
            i32x4 Af[MT];
            #pragma unroll
            for (int mt = 0; mt < MT; mt++)
                Af[mt] = *(const i32x4*)&X[(CH8 + ch) * PSTR + ao[mt]];
            #pragma unroll
            for (int mt = 0; mt < MT; mt++)
                #pragma unroll
                for (int nt = 0; nt < NT; nt++)
                    accH[mt][nt] = __builtin_amdgcn_mfma_i32_16x16x64_i8(
                        Af[mt], Bb[cur][nt], accH[mt][nt], 0, 0, 0);
        }
    }

    // epilogue: sum = 256*accH + accL (exact i32); pool in int; dq + bias + relu
    const double c2 = scr[2];
    const float alpha = (float)(scr[1] / (c2 > 1.0 ? c2 : 1.0));
    const float dq = alpha / S;
    float tmax = 0.f;
    #pragma unroll
    for (int mt = 0; mt < MT; mt++) {
        const int pp = (wm * MT + mt) * 4 + kg;
        const int lph = pp / PO, lpw = pp % PO;
        const int gpp = (hb * POR + lph) * PO + lpw;
        unsigned short* yr = yout + ((long)bimg * (PO * PO) + gpp) * (2 * CO);
        #pragma unroll
        for (int nt = 0; nt < NT; nt++) {
            const int co = (wn * NT + nt) * 16 + lm;
            const i32x4 aL = accL[mt][nt], aH = accH[mt][nt];
            int s0 = aH[0] * 256 + aL[0];
            int s1 = aH[1] * 256 + aL[1];
            int s2 = aH[2] * 256 + aL[2];
            int s3 = aH[3] * 256 + aL[3];
            int sm = s0 > s1 ? s0 : s1;
            int sn = s2 > s3 ? s2 : s3;
            sm = sm > sn ? sm : sn;
            float o = fmaxf(dq * (float)sm + bias[co], 0.f);
            tmax = fmaxf(tmax, o);
            unsigned short hi = f2bf(o);
            unsigned short lo = f2bf(o - bf2f(hi));
            yr[co] = hi;
            yr[CO + co] = lo;
        }
    }
    if (amax_out) {
        #pragma unroll
        for (int off = 32; off > 0; off >>= 1)
            tmax = fmaxf(tmax, __shfl_down(tmax, off, 64));
        if (lane == 0) redm[wid] = tmax;
        __syncthreads();
        if (tid == 0) {
            float m = fmaxf(fmaxf(redm[0], redm[1]), fmaxf(redm[2], redm[3]));
            atomicMax(amax_out, __float_as_int(m));
        }
    }
}

// ---------------------------------------------------------------------------
// fc1 MFMA (bf16): K=8192 hi/lo slots, split-K, reg-pipelined.
// ---------------------------------------------------------------------------
template <int S>
__global__ __launch_bounds__(256) void fc1_mfma(
        const unsigned short* __restrict__ A,
        const unsigned short* __restrict__ Bw,
        float* __restrict__ parts) {
    constexpr int KCH = 8192 / S;
    constexpr int NSTEP = KCH / 32;
    const int m0 = blockIdx.x * 128;
    const int n0 = blockIdx.y * 128;
    const int s = blockIdx.z;
    const int tid = threadIdx.x;
    const int lane = tid & 63, wid = tid >> 6;
    const int wm = wid >> 1, wn = wid & 1;
    const int lm = lane & 15, kg = lane >> 4;

    const long k0 = (long)s * KCH + kg * 8;
    const unsigned short* ap[4];
    const unsigned short* bp[4];
    #pragma unroll
    for (int t = 0; t < 4; t++) {
        ap[t] = A + (long)(m0 + wm * 64 + t * 16 + lm) * 8192 + k0;
        bp[t] = Bw + (long)(n0 + wn * 64 + t * 16 + lm) * 8192 + k0;
    }

    f32x4 acc[4][4] = {};
    short8 Ab[2][4], Bb[2][4];
    #pragma unroll
    for (int t = 0; t < 4; t++) {
        Ab[0][t] = *(const short8*)(ap[t]);
        Bb[0][t] = *(const short8*)(bp[t]);
    }

    #pragma unroll 2
    for (int st = 0; st < NSTEP; ++st) {
        const int cur = st & 1, nxt = cur ^ 1;
        if (st + 1 < NSTEP) {
            const int off = (st + 1) * 32;
            #pragma unroll
            for (int t = 0; t < 4; t++) {
                Ab[nxt][t] = *(const short8*)(ap[t] + off);
                Bb[nxt][t] = *(const short8*)(bp[t] + off);
            }
        }
        #pragma unroll
        for (int mt = 0; mt < 4; mt++)
            #pragma unroll
            for (int nt = 0; nt < 4; nt++)
                acc[mt][nt] = __builtin_amdgcn_mfma_f32_16x16x32_bf16(
                    Ab[cur][mt], Bb[cur][nt], acc[mt][nt], 0, 0, 0);
    }

    #pragma unroll
    for (int mt = 0; mt < 4; mt++) {
        #pragma unroll
        for (int r = 0; r < 4; r++) {
            const int b = m0 + wm * 64 + mt * 16 + kg * 4 + r;
            #pragma unroll
            for (int nt = 0; nt < 4; nt++) {
                const int j = n0 + wn * 64 + nt * 16 + lm;
                parts[((long)s * 1024 + b) * 256 + j] = acc[mt][nt][r];
            }
        }
    }
}

// ---------------------------------------------------------------------------
// Fused fc1-reduce + fc2: block = 1 image. Phase 1: reduce split-K parts,
// alpha+bias+relu -> LDS. Phase 2: 10 wave-level dots with wtf2.
// ---------------------------------------------------------------------------
template <int S>
__global__ __launch_bounds__(256) void fc2_fused(
        const float* __restrict__ parts,
        const double* __restrict__ scr,      // fc1 stats {sum, msum, count}
        const float* __restrict__ bf1v,
        const float* __restrict__ wtf2,
        const float* __restrict__ bf2v,
        float* __restrict__ out) {
    __shared__ float sf[256];
    const int b = blockIdx.x;
    const int j = threadIdx.x;
    float s = 0.f;
    #pragma unroll
    for (int p = 0; p < S; p++)
        s += parts[(long)p * 262144 + (long)b * 256 + j];
    const double c2 = scr[2];
    const float alpha = (float)(scr[1] / (c2 > 1.0 ? c2 : 1.0));
    sf[j] = fmaxf(alpha * s + bf1v[j], 0.f);
    __syncthreads();
    const int lane = threadIdx.x & 63, wid = threadIdx.x >> 6;
    for (int k = wid; k < 10; k += 4) {
        const float* wr = wtf2 + k * 256;
        float acc = 0.f;
        #pragma unroll
        for (int t = 0; t < 4; t++)
            acc += sf[lane + t * 64] * wr[lane + t * 64];
        #pragma unroll
        for (int off = 32; off > 0; off >>= 1)
            acc += __shfl_down(acc, off, 64);
        if (lane == 0) out[(long)b * 10 + k] = acc + bf2v[k];
    }
}

extern "C" void kernel_launch(void* const* d_in, const int* in_sizes, int n_in,
                              void* d_out, int out_size, void* d_ws, size_t ws_size,
                              hipStream_t stream) {
    const float* x   = (const float*)d_in[0];
    const float* w1  = (const float*)d_in[1];
    const float* b1  = (const float*)d_in[2];
    const float* w2  = (const float*)d_in[3];
    const float* b2  = (const float*)d_in[4];
    const float* w3  = (const float*)d_in[5];
    const float* b3  = (const float*)d_in[6];
    const float* wf1 = (const float*)d_in[7];
    const float* bf1 = (const float*)d_in[8];
    const float* wf2 = (const float*)d_in[9];
    const float* bf2 = (const float*)d_in[10];
    float* out = (float*)d_out;
    float* ws = (float*)d_ws;

    const int B = 1024;

    signed char*    w1b   = (signed char*)(ws + WS_W1B);
    signed char*    w2p8  = (signed char*)(ws + WS_W2P);
    signed char*    w3p8  = (signed char*)(ws + WS_W3P);
    unsigned short* wtf1b = (unsigned short*)(ws + WS_WTF1);
    float*          wtf2  = ws + WS_WTF2;
    float*          a1f   = ws + WS_A1;
    unsigned short* a2p   = (unsigned short*)(ws + WS_A2);
    unsigned short* a3p   = (unsigned short*)(ws + WS_A3);
    double*         scr   = (double*)(ws + WS_SCR);
    int*            iscr  = (int*)(scr + 20);
    int*            amaxx = iscr;           // amax(x)
    int*            amax1 = iscr + 1;       // amax(a1)
    int*            amax2 = iscr + 2;       // amax(a2)
    float*          parts = ws + WS_A1;     // alias: a1 dead after conv2

    hipMemsetAsync(scr, 0, 22 * sizeof(double), stream);
    hipMemsetAsync(w1b, 0, 8192, stream);   // BL/BH zero padding

    TernArgs ta;
    ta.w[0] = w1;  ta.n[0] = 64 * 27;
    ta.w[1] = w2;  ta.n[1] = 128 * 64 * 9;
    ta.w[2] = w3;  ta.n[2] = 256 * 128 * 9;
    ta.w[3] = wf1; ta.n[3] = 256 * 4096;
    ta.w[4] = wf2; ta.n[4] = 10 * 256;
    ta.w[5] = x;   ta.n[5] = 1024 * 3 * 32 * 32;   // amax(x)

    hipLaunchKernelGGL(tern_stats1, dim3(128, 6), dim3(256), 0, stream, ta, scr);
    hipLaunchKernelGGL(tern_stats2, dim3(128, 5), dim3(256), 0, stream, ta, scr);
    hipLaunchKernelGGL(tern_write_all, dim3(128, 5), dim3(256), 0, stream,
                       ta, scr, w1b, w2p8, w3p8, wtf1b, wtf2);

    // conv1: i8 MFMA, 1 block per image -> a1 fp32 rows + amax1
    hipLaunchKernelGGL(conv1_i8, dim3(B), dim3(256), 0, stream,
                       x, w1b, b1, scr + 0, amaxx, amax1, a1f);

    // conv2: CI=64, HI=16, CO=128, HB=2, WM=2, WN=2, fp32 input -> 2048 blocks
    hipLaunchKernelGGL((conv_i8<64, 16, 128, 2, 2, 2, true>), dim3(B * 2),
                       dim3(256), 0, stream, a1f, w2p8, b2, scr + 4, amax1,
                       amax2, a2p);

    // conv3: CI=128, HI=8, CO=256, HB=1, WM=1, WN=4 (all co) -> 1024 blocks
    hipLaunchKernelGGL((conv_i8<128, 8, 256, 1, 1, 4, false>), dim3(B),
                       dim3(256), 0, stream, a2p, w3p8, b3, scr + 8, amax2,
                       (int*)nullptr, a3p);

    // fc1: MFMA split-K
    hipLaunchKernelGGL((fc1_mfma<FC1_S>), dim3(8, 2, FC1_S), dim3(256), 0, stream,
                       a3p, wtf1b, parts);

    // fused fc1-reduce + fc2
    hipLaunchKernelGGL((fc2_fused<FC1_S>), dim3(B), dim3(256), 0, stream,
                       parts, scr + 12, bf1, wtf2, bf2, out);
}

// Round 15
// 282.206 us; speedup vs baseline: 1.1718x; 1.0117x over previous
//
#include <hip/hip_runtime.h>
#include <hip/hip_bf16.h>

// ---------------------------------------------------------------------------
// TernaryCIFAR10Net on MI355X — Round 15:
//   conv_i8 staging via __builtin_amdgcn_global_load_lds: input rows (4096 B
//   contiguous for both conv2 and conv3) are async-DMA'd into a RAW LDS
//   region (zero VGPR, max memory-level parallelism), then quantized
//   LDS->LDS into the swizzled X planes. conv3 uses 2 row-phases to stay
//   under the 64KB static LDS limit. K-loop/epilogue unchanged from R14.
//   conv1 (i8 MFMA K-free), fc1_mfma, fc2_fused, ternarize unchanged.
// ---------------------------------------------------------------------------

typedef __attribute__((ext_vector_type(8))) short short8;
typedef __attribute__((ext_vector_type(4))) float f32x4;
typedef __attribute__((ext_vector_type(4))) int i32x4;

#define GLOAD_LDS16(g, l)                                              \
    __builtin_amdgcn_global_load_lds(                                  \
        (const __attribute__((address_space(1))) void*)(g),            \
        (__attribute__((address_space(3))) void*)(l), 16, 0, 0)

__device__ __forceinline__ unsigned short f2bf(float x) {
    unsigned u = __float_as_uint(x);
    return (unsigned short)((u + 0x7fffu + ((u >> 16) & 1u)) >> 16);  // RNE
}
__device__ __forceinline__ float bf2f(unsigned short b) {
    return __uint_as_float(((unsigned)b) << 16);
}

// workspace layout (4-byte units)
#define WS_W1B   0
#define N_W1B    2048                  // 8192 B: [2][64 co][64 k] i8 signs
#define WS_W2P   (WS_W1B + N_W1B)
#define N_W2P    (9*128*64)
#define WS_W3P   (WS_W2P + N_W2P)
#define N_W3P    (9*256*128)
#define WS_WTF1  (WS_W3P + N_W3P)
#define N_WTF1   (256*4096)            // ushort signs [256][8192]
#define WS_WTF2  (WS_WTF1 + N_WTF1)
#define N_WTF2   (10*256)
#define WS_A1    (WS_WTF2 + N_WTF2)
#define N_A1     (1024*256*64)         // a1: [B][256px][64 fp32]; parts alias
#define WS_A2    (WS_A1 + N_A1)
#define N_A2     (1024*64*128)         // a2: [B][64px][256 ushort] (hi/lo bf16)
#define WS_A3    (WS_A2 + N_A2)
#define N_A3     (1024*16*256)         // a3: [B][16px][512 ushort]
#define WS_F1    (WS_A3 + N_A3)
#define N_F1     (1024*256)
#define WS_SCR   (WS_F1 + N_F1)

#define FC1_S    16

struct TernArgs {
    const float* w[6];
    int n[6];
};

// ---------------------------------------------------------------------------
// Stats pass 1: wi<5 -> sum|w|; wi==5 -> amax(x) -> ((int*)(scr+20))[0].
// ---------------------------------------------------------------------------
__global__ void tern_stats1(TernArgs ta, double* __restrict__ scr) {
    const int wi = blockIdx.y;
    const float* __restrict__ w = ta.w[wi];
    const int n = ta.n[wi];
    __shared__ double red[4];
    const int lane = threadIdx.x & 63, wv = threadIdx.x >> 6;
    if (wi == 5) {
        float m = 0.f;
        for (int i = blockIdx.x * blockDim.x + threadIdx.x; i < n;
             i += gridDim.x * blockDim.x)
            m = fmaxf(m, fabsf(w[i]));
        #pragma unroll
        for (int off = 32; off > 0; off >>= 1)
            m = fmaxf(m, __shfl_down(m, off, 64));
        if (lane == 0) red[wv] = (double)m;
        __syncthreads();
        if (threadIdx.x == 0) {
            float mm = (float)fmax(fmax(red[0], red[1]), fmax(red[2], red[3]));
            atomicMax((int*)(scr + 20), __float_as_int(mm));
        }
        return;
    }
    double s = 0.0;
    for (int i = blockIdx.x * blockDim.x + threadIdx.x; i < n;
         i += gridDim.x * blockDim.x)
        s += (double)fabsf(w[i]);
    #pragma unroll
    for (int off = 32; off > 0; off >>= 1) s += __shfl_down(s, off, 64);
    if (lane == 0) red[wv] = s;
    __syncthreads();
    if (threadIdx.x == 0)
        atomicAdd(scr + wi * 4, red[0] + red[1] + red[2] + red[3]);
}

__global__ void tern_stats2(TernArgs ta, double* __restrict__ scr) {
    const int wi = blockIdx.y;
    const float* __restrict__ w = ta.w[wi];
    const int n = ta.n[wi];
    const float delta = (float)(0.7 * scr[wi * 4] / (double)n);
    double ms = 0.0, cnt = 0.0;
    for (int i = blockIdx.x * blockDim.x + threadIdx.x; i < n;
         i += gridDim.x * blockDim.x) {
        float a = fabsf(w[i]);
        if (a > delta) { ms += (double)a; cnt += 1.0; }
    }
    #pragma unroll
    for (int off = 32; off > 0; off >>= 1) {
        ms += __shfl_down(ms, off, 64);
        cnt += __shfl_down(cnt, off, 64);
    }
    __shared__ double redm[4], redc[4];
    const int lane = threadIdx.x & 63, wv = threadIdx.x >> 6;
    if (lane == 0) { redm[wv] = ms; redc[wv] = cnt; }
    __syncthreads();
    if (threadIdx.x == 0) {
        atomicAdd(scr + wi * 4 + 1, redm[0] + redm[1] + redm[2] + redm[3]);
        atomicAdd(scr + wi * 4 + 2, redc[0] + redc[1] + redc[2] + redc[3]);
    }
}

// ---------------------------------------------------------------------------
// Fused writer (same as R14).
// ---------------------------------------------------------------------------
__global__ void tern_write_all(TernArgs ta, const double* __restrict__ scr,
                               signed char* __restrict__ w1b,
                               signed char* __restrict__ w2p8,
                               signed char* __restrict__ w3p8,
                               unsigned short* __restrict__ wtf1b,
                               float* __restrict__ wtf2) {
    const int wi = blockIdx.y;
    const float* __restrict__ w = ta.w[wi];
    const int n = ta.n[wi];
    const double* sc = scr + wi * 4;
    const float delta = (float)(0.7 * sc[0] / (double)n);
    const int i0 = blockIdx.x * blockDim.x + threadIdx.x;
    const int stride = gridDim.x * blockDim.x;

    if (wi == 0) {
        for (int i = i0; i < n; i += stride) {       // n = 1728 = 64*27
            const int co = i / 27;
            const int kp = i % 27;                    // ci*9 + tap
            float v = w[i];
            signed char s = (fabsf(v) > delta) ? (v > 0.0f ? 1 : -1) : 0;
            w1b[co * 64 + kp] = s;                    // BL, k = kp
            w1b[4096 + co * 64 + 32 + kp] = s;        // BH, k = 32+kp
        }
    } else if (wi == 4) {
        const double c = sc[2];
        const float alpha = (float)(sc[1] / (c > 1.0 ? c : 1.0));
        for (int i = i0; i < n; i += stride) {
            float v = w[i];
            wtf2[i] = (fabsf(v) > delta) ? (v > 0.0f ? alpha : -alpha) : 0.0f;
        }
    } else if (wi == 1 || wi == 2) {
        const int CIc = (wi == 1) ? 64 : 128;
        const int COc = (wi == 1) ? 128 : 256;
        signed char* dst = (wi == 1) ? w2p8 : w3p8;
        for (int i = i0; i < n; i += stride) {
            const int co = i / (CIc * 9);
            const int r = i % (CIc * 9);
            const int ci = r / 9, tap = r % 9;
            float v = w[i];
            signed char s = (fabsf(v) > delta) ? (v > 0.0f ? 1 : -1) : 0;
            dst[(tap * COc + co) * CIc + ci] = s;
        }
    } else {  // wi == 3: fc1 signs, hi and lo slots
        for (int i = i0; i < n; i += stride) {
            const int j = i >> 12;
            const int k = i & 4095;
            const int c = k >> 4, px = k & 15;
            float v = w[i];
            unsigned short s = (fabsf(v) > delta) ? (v > 0.0f ? 0x3f80 : 0xbf80) : 0;
            unsigned short* row = wtf1b + ((long)j << 13) + px * 512 + c;
            row[0] = s;
            row[256] = s;
        }
    }
}

// ---------------------------------------------------------------------------
// conv1 (unchanged from R12): i8 MFMA, no K-loop, block = 1 image.
// ---------------------------------------------------------------------------
__global__ __launch_bounds__(256) void conv1_i8(
        const float* __restrict__ x,
        const signed char* __restrict__ w1b,   // [2][64 co][64 k]
        const float* __restrict__ bias,
        const double* __restrict__ scr,        // w1 stats {sum, msum, count}
        const int* __restrict__ amax_x,
        int* __restrict__ amax_out,
        float* __restrict__ y) {
    constexpr int PL = 3472;                   // plane stride bytes
    __shared__ __align__(16) char X[2 * PL];
    __shared__ float redm[4];

    const int b = blockIdx.x;
    const int tid = threadIdx.x;
    const float S = 32512.0f / fmaxf(__int_as_float(*amax_x), 1e-30f);

    for (int i = tid; i < 2 * PL / 16; i += 256)
        ((int4*)X)[i] = make_int4(0, 0, 0, 0);
    __syncthreads();

    for (int i = tid; i < 768; i += 256) {
        const float4 v = ((const float4*)(x + (long)b * 3072))[i];
        const int e = i * 4;
        const int ci = e >> 10;
        const int rem = e & 1023;
        const int h = rem >> 5, w = rem & 31;
        const int base = ci * 1156 + (h + 1) * 34 + (w + 1);
        const float f[4] = {v.x, v.y, v.z, v.w};
        #pragma unroll
        for (int j = 0; j < 4; j++) {
            const int q = __float2int_rn(f[j] * S);
            const int ql = (q << 24) >> 24;
            const int qh = (q - ql) >> 8;
            X[base + j] = (char)ql;
            X[PL + base + j] = (char)qh;
        }
    }
    __syncthreads();

    const int lane = tid & 63;
    const int wid = tid >> 6;
    const int lm = lane & 15;
    const int kg = lane >> 4;

    const int poff = (kg >= 2) ? PL : 0;
    int cst[16];
    #pragma unroll
    for (int j = 0; j < 16; j++) {
        const int kp = (kg & 1) * 16 + j;
        cst[j] = (kp < 27)
                     ? ((kp / 9) * 1156 + ((kp % 9) / 3) * 34 + (kp % 9) % 3)
                     : 0;
    }

    i32x4 BL[4], BH[4];
    #pragma unroll
    for (int nt = 0; nt < 4; nt++) {
        const int co = nt * 16 + lm;
        BL[nt] = *(const i32x4*)(w1b + (long)co * 64 + kg * 16);
        BH[nt] = *(const i32x4*)(w1b + 4096 + (long)co * 64 + kg * 16);
    }

    const double c2 = scr[2];
    const float alpha = (float)(scr[1] / (c2 > 1.0 ? c2 : 1.0));
    const float dq = alpha / S;
    float tmax = 0.f;
    float* yb = y + (long)b * 256 * 64;

    for (int tt = 0; tt < 16; ++tt) {
        const int t = wid * 16 + tt;
        const int pp = t * 4 + (lm >> 2);
        const int sub = lm & 3;
        const int h = 2 * (pp >> 4) + (sub >> 1);
        const int w = 2 * (pp & 15) + (sub & 1);
        const int base = poff + h * 34 + w;
        unsigned d[4] = {0u, 0u, 0u, 0u};
        #pragma unroll
        for (int j = 0; j < 16; j++) {
            const unsigned byte = (unsigned char)X[base + cst[j]];
            d[j >> 2] |= byte << ((j & 3) * 8);
        }
        i32x4 Af;
        Af[0] = (int)d[0]; Af[1] = (int)d[1];
        Af[2] = (int)d[2]; Af[3] = (int)d[3];

        const int opp = t * 4 + kg;
        float* yr = yb + (long)opp * 64;
        #pragma unroll
        for (int nt = 0; nt < 4; nt++) {
            i32x4 aL = 0, aH = 0;
            aL = __builtin_amdgcn_mfma_i32_16x16x64_i8(Af, BL[nt], aL, 0, 0, 0);
            aH = __builtin_amdgcn_mfma_i32_16x16x64_i8(Af, BH[nt], aH, 0, 0, 0);
            const int s0 = aH[0] * 256 + aL[0];
            const int s1 = aH[1] * 256 + aL[1];
            const int s2 = aH[2] * 256 + aL[2];
            const int s3 = aH[3] * 256 + aL[3];
            int sm = s0 > s1 ? s0 : s1;
            const int sn = s2 > s3 ? s2 : s3;
            sm = sm > sn ? sm : sn;
            const int co = nt * 16 + lm;
            const float o = fmaxf(dq * (float)sm + bias[co], 0.f);
            tmax = fmaxf(tmax, o);
            yr[co] = o;
        }
    }

    #pragma unroll
    for (int off = 32; off > 0; off >>= 1)
        tmax = fmaxf(tmax, __shfl_down(tmax, off, 64));
    if (lane == 0) redm[wid] = tmax;
    __syncthreads();
    if (tid == 0) {
        float m = fmaxf(fmaxf(redm[0], redm[1]), fmaxf(redm[2], redm[3]));
        atomicMax(amax_out, __float_as_int(m));
    }
}

// ---------------------------------------------------------------------------
// int8 MFMA conv, round-15: staging via global_load_lds into RAW (rows are
// 4096 B contiguous for both convs), then LDS->LDS quantize into swizzled X.
// NPH row-phases keep static LDS under 64 KB. K-loop: MT=4 x NT=4, B
// double-buffered, acc in 128 AGPRs; __launch_bounds__(256,2).
// ---------------------------------------------------------------------------
template <int CI, int HI, int CO, int HB, int WM, int WN, bool INF32, int NPH>
__global__ __launch_bounds__(256, 2) void conv_i8(
        const void* __restrict__ xin,
        const signed char* __restrict__ wp,     // [9][CO][CI] int8 signs
        const float* __restrict__ bias,
        const double* __restrict__ scr,         // layer {_, msum, count}
        const int* __restrict__ amax_in,
        int* __restrict__ amax_out,             // nullptr if unused
        unsigned short* __restrict__ yout) {
    constexpr int CH8 = CI / 64;
    constexpr int NITER = 9 * CH8;
    constexpr int HR = HI / HB;
    constexpr int ROWS = HR + 2;
    constexpr int COLS = HI + 2;
    constexpr int NPIX = ROWS * COLS;
    constexpr int PSTR = NPIX * 64 + 32;    // bytes per g-plane
    constexpr int PO = HI / 2;
    constexpr int POR = HR / 2;
    constexpr int MT = 4, NT = 4;
    constexpr int RWB = HI * CI * 4;        // bytes per input row (= 4096)
    constexpr int RR = (ROWS + NPH - 1) / NPH;
    static_assert(WM * WN == 4, "4 waves");
    static_assert(WM * 64 == HR * HI, "M covers slab pixels");
    static_assert(WN * 64 == CO, "N covers all co");
    static_assert(RWB == 4096, "row must be 4096 B");

    __shared__ __align__(16) char X[2 * CH8 * PSTR];
    __shared__ __align__(16) char RAW[RR * RWB];
    __shared__ float redm[4];

    const int bimg = blockIdx.x / HB;
    const int hb = blockIdx.x % HB;
    const int tid = threadIdx.x;
    const int lane = tid & 63;
    const int wid = tid >> 6;

    const float S = 32512.0f / fmaxf(__int_as_float(*amax_in), 1e-30f);

    // halo zero of X (borders only; interior fully written by quantize)
    constexpr int HALO = 2 * COLS + 2 * (ROWS - 2);
    for (int i = tid; i < HALO * 2 * CH8 * 4; i += 256) {
        const int u = i & 3;
        const int t = i >> 2;
        const int g = t % (2 * CH8);
        const int hp = t / (2 * CH8);
        int p;
        if (hp < COLS) p = hp;
        else if (hp < 2 * COLS) p = (ROWS - 1) * COLS + (hp - COLS);
        else {
            const int e = hp - 2 * COLS;
            p = (1 + (e >> 1)) * COLS + ((e & 1) ? (COLS - 1) : 0);
        }
        *(int4*)&X[g * PSTR + p * 64 + u * 16] = make_int4(0, 0, 0, 0);
    }

    // staging phases: async rows -> RAW, then quantize RAW -> X
    for (int ph = 0; ph < NPH; ph++) {
        const int r0 = ph * RR;
        const int rend = (r0 + RR < ROWS) ? (r0 + RR) : ROWS;
        for (int r = r0; r < rend; r++) {
            const int h = hb * HR + r - 1;
            const int rl = r - r0;
            if ((unsigned)h >= (unsigned)HI) {
                *(int4*)&RAW[rl * RWB + tid * 16] = make_int4(0, 0, 0, 0);
            } else if (wid == (r & 3)) {
                const char* grow = (const char*)xin +
                                   ((long)(bimg * HI + h)) * RWB;
                #pragma unroll
                for (int j = 0; j < RWB / 1024; j++)
                    GLOAD_LDS16(grow + j * 1024 + lane * 16,
                                &RAW[rl * RWB + j * 1024]);
            }
        }
        __syncthreads();

        const int NIT = (rend - r0) * HI * (CI / 8);
        for (int i = tid; i < NIT; i += 256) {
            const int q8 = i % (CI / 8);
            const int t = i / (CI / 8);
            const int c = t % HI;
            const int rl = t / HI;
            const int r = r0 + rl;
            float f[8];
            if (INF32) {
                const float* pf =
                    (const float*)&RAW[rl * RWB + c * (CI * 4) + q8 * 32];
                const float4 va = *(const float4*)(pf);
                const float4 vb = *(const float4*)(pf + 4);
                f[0] = va.x; f[1] = va.y; f[2] = va.z; f[3] = va.w;
                f[4] = vb.x; f[5] = vb.y; f[6] = vb.z; f[7] = vb.w;
            } else {
                const uint4 vh =
                    *(const uint4*)&RAW[rl * RWB + c * (CI * 4) + q8 * 16];
                const uint4 vl =
                    *(const uint4*)&RAW[rl * RWB + c * (CI * 4) + CI * 2 +
                                        q8 * 16];
                const unsigned* hw = (const unsigned*)&vh;
                const unsigned* lw = (const unsigned*)&vl;
                #pragma unroll
                for (int j = 0; j < 8; j++) {
                    const unsigned hu = (j & 1) ? (hw[j >> 1] >> 16)
                                                : (hw[j >> 1] & 0xffffu);
                    const unsigned lu = (j & 1) ? (lw[j >> 1] >> 16)
                                                : (lw[j >> 1] & 0xffffu);
                    f[j] = __uint_as_float(hu << 16) +
                           __uint_as_float(lu << 16);
                }
            }
            unsigned pl0 = 0, pl1 = 0, ph0 = 0, ph1 = 0;
            #pragma unroll
            for (int j = 0; j < 8; j++) {
                const int qi = (int)(f[j] * S + 0.5f);  // inputs >= 0
                const int ql = (qi << 24) >> 24;
                const int qh = (qi - ql) >> 8;
                const int sh = (j & 3) * 8;
                if (j < 4) {
                    pl0 |= (unsigned)(ql & 255) << sh;
                    ph0 |= (unsigned)(qh & 255) << sh;
                } else {
                    pl1 |= (unsigned)(ql & 255) << sh;
                    ph1 |= (unsigned)(qh & 255) << sh;
                }
            }
            const int p = r * COLS + c + 1;
            const int ch = q8 / (64 / 8);            // c8 = q8*8; ch = c8/64
            const int cc = (q8 * 8) & 63;
            const int slot = ((cc >> 4) + (p >> 1)) & 3;
            const int base = p * 64 + slot * 16 + (cc & 15);
            *(uint2*)&X[ch * PSTR + base] = make_uint2(pl0, pl1);
            *(uint2*)&X[(CH8 + ch) * PSTR + base] = make_uint2(ph0, ph1);
        }
        __syncthreads();
    }

    const int wm = (WM == 1) ? 0 : (wid >> 1);
    const int wn = (WM == 1) ? wid : (wid & 1);
    const int lm = lane & 15;
    const int kg = lane >> 4;

    int pb[MT];
    #pragma unroll
    for (int mt = 0; mt < MT; mt++) {
        const int m = (wm * MT + mt) * 16 + lm;
        const int pp = m >> 2, sub = m & 3;
        const int lph = pp / PO, lpw = pp % PO;
        const int h = 2 * lph + (sub >> 1);
        const int w = 2 * lpw + (sub & 1);
        pb[mt] = h * COLS + w;
    }
    const signed char* bp[NT];
    #pragma unroll
    for (int nt = 0; nt < NT; nt++) {
        const int co = (wn * NT + nt) * 16 + lm;
        bp[nt] = wp + (long)co * CI + kg * 16;
    }

    i32x4 accL[MT][NT], accH[MT][NT];
    #pragma unroll
    for (int mt = 0; mt < MT; mt++)
        #pragma unroll
        for (int nt = 0; nt < NT; nt++) { accL[mt][nt] = 0; accH[mt][nt] = 0; }

    i32x4 Bb[2][NT];
    #pragma unroll
    for (int nt = 0; nt < NT; nt++) Bb[0][nt] = *(const i32x4*)(bp[nt]);

    #pragma unroll 2
    for (int it = 0; it < NITER; ++it) {
        const int cur = it & 1, nxt = cur ^ 1;
        if (it + 1 < NITER) {
            const int it1 = it + 1;
            const int tap = it1 / CH8, ch1 = it1 % CH8;
            const int woff = tap * CO * CI + ch1 * 64;
            #pragma unroll
            for (int nt = 0; nt < NT; nt++)
                Bb[nxt][nt] = *(const i32x4*)(bp[nt] + woff);
        }
        const int tap = it / CH8, ch = it % CH8;
        const int dtap = (tap / 3) * COLS + (tap % 3);
        int ao[MT];
        #pragma unroll
        for (int mt = 0; mt < MT; mt++) {
            const int p = pb[mt] + dtap;
            ao[mt] = p * 64 + (((kg + (p >> 1)) & 3) << 4);
        }
        {
            i32x4 Af[MT];
            #pragma unroll
            for (int mt = 0; mt < MT; mt++)
                Af[mt] = *(const i32x4*)&X[ch * PSTR + ao[mt]];
            #pragma unroll
            for (int mt = 0; mt < MT; mt++)
                #pragma unroll
                for (int nt = 0; nt < NT; nt++)
                    accL[mt][nt] = __builtin_amdgcn_mfma_i32_16x16x64_i8(
                        Af[mt], Bb[cur][nt], accL[mt][nt], 0, 0, 0);
        }
        {
            i32x4 Af[MT];
            #pragma unroll
            for (int mt = 0; mt < MT; mt++)
                Af[mt] = *(const i32x4*)&X[(CH8 + ch) * PSTR + ao[mt]];
            #pragma unroll
            for (int mt = 0; mt < MT; mt++)
                #pragma unroll
                for (int nt = 0; nt < NT; nt++)
                    accH[mt][nt] = __builtin_amdgcn_mfma_i32_16x16x64_i8(
                        Af[mt], Bb[cur][nt], accH[mt][nt], 0, 0, 0);
        }
    }

    // epilogue: sum = 256*accH + accL (exact i32); pool in int; dq + bias + relu
    const double c2 = scr[2];
    const float alpha = (float)(scr[1] / (c2 > 1.0 ? c2 : 1.0));
    const float dq = alpha / S;
    float tmax = 0.f;
    #pragma unroll
    for (int mt = 0; mt < MT; mt++) {
        const int pp = (wm * MT + mt) * 4 + kg;
        const int lph = pp / PO, lpw = pp % PO;
        const int gpp = (hb * POR + lph) * PO + lpw;
        unsigned short* yr = yout + ((long)bimg * (PO * PO) + gpp) * (2 * CO);
        #pragma unroll
        for (int nt = 0; nt < NT; nt++) {
            const int co = (wn * NT + nt) * 16 + lm;
            const i32x4 aL = accL[mt][nt], aH = accH[mt][nt];
            int s0 = aH[0] * 256 + aL[0];
            int s1 = aH[1] * 256 + aL[1];
            int s2 = aH[2] * 256 + aL[2];
            int s3 = aH[3] * 256 + aL[3];
            int sm = s0 > s1 ? s0 : s1;
            int sn = s2 > s3 ? s2 : s3;
            sm = sm > sn ? sm : sn;
            float o = fmaxf(dq * (float)sm + bias[co], 0.f);
            tmax = fmaxf(tmax, o);
            unsigned short hi = f2bf(o);
            unsigned short lo = f2bf(o - bf2f(hi));
            yr[co] = hi;
            yr[CO + co] = lo;
        }
    }
    if (amax_out) {
        #pragma unroll
        for (int off = 32; off > 0; off >>= 1)
            tmax = fmaxf(tmax, __shfl_down(tmax, off, 64));
        if (lane == 0) redm[wid] = tmax;
        __syncthreads();
        if (tid == 0) {
            float m = fmaxf(fmaxf(redm[0], redm[1]), fmaxf(redm[2], redm[3]));
            atomicMax(amax_out, __float_as_int(m));
        }
    }
}

// ---------------------------------------------------------------------------
// fc1 MFMA (bf16): K=8192 hi/lo slots, split-K, reg-pipelined.
// ---------------------------------------------------------------------------
template <int S>
__global__ __launch_bounds__(256) void fc1_mfma(
        const unsigned short* __restrict__ A,
        const unsigned short* __restrict__ Bw,
        float* __restrict__ parts) {
    constexpr int KCH = 8192 / S;
    constexpr int NSTEP = KCH / 32;
    const int m0 = blockIdx.x * 128;
    const int n0 = blockIdx.y * 128;
    const int s = blockIdx.z;
    const int tid = threadIdx.x;
    const int lane = tid & 63, wid = tid >> 6;
    const int wm = wid >> 1, wn = wid & 1;
    const int lm = lane & 15, kg = lane >> 4;

    const long k0 = (long)s * KCH + kg * 8;
    const unsigned short* ap[4];
    const unsigned short* bp[4];
    #pragma unroll
    for (int t = 0; t < 4; t++) {
        ap[t] = A + (long)(m0 + wm * 64 + t * 16 + lm) * 8192 + k0;
        bp[t] = Bw + (long)(n0 + wn * 64 + t * 16 + lm) * 8192 + k0;
    }

    f32x4 acc[4][4] = {};
    short8 Ab[2][4], Bb[2][4];
    #pragma unroll
    for (int t = 0; t < 4; t++) {
        Ab[0][t] = *(const short8*)(ap[t]);
        Bb[0][t] = *(const short8*)(bp[t]);
    }

    #pragma unroll 2
    for (int st = 0; st < NSTEP; ++st) {
        const int cur = st & 1, nxt = cur ^ 1;
        if (st + 1 < NSTEP) {
            const int off = (st + 1) * 32;
            #pragma unroll
            for (int t = 0; t < 4; t++) {
                Ab[nxt][t] = *(const short8*)(ap[t] + off);
                Bb[nxt][t] = *(const short8*)(bp[t] + off);
            }
        }
        #pragma unroll
        for (int mt = 0; mt < 4; mt++)
            #pragma unroll
            for (int nt = 0; nt < 4; nt++)
                acc[mt][nt] = __builtin_amdgcn_mfma_f32_16x16x32_bf16(
                    Ab[cur][mt], Bb[cur][nt], acc[mt][nt], 0, 0, 0);
    }

    #pragma unroll
    for (int mt = 0; mt < 4; mt++) {
        #pragma unroll
        for (int r = 0; r < 4; r++) {
            const int b = m0 + wm * 64 + mt * 16 + kg * 4 + r;
            #pragma unroll
            for (int nt = 0; nt < 4; nt++) {
                const int j = n0 + wn * 64 + nt * 16 + lm;
                parts[((long)s * 1024 + b) * 256 + j] = acc[mt][nt][r];
            }
        }
    }
}

// ---------------------------------------------------------------------------
// Fused fc1-reduce + fc2 (unchanged from R14).
// ---------------------------------------------------------------------------
template <int S>
__global__ __launch_bounds__(256) void fc2_fused(
        const float* __restrict__ parts,
        const double* __restrict__ scr,      // fc1 stats {sum, msum, count}
        const float* __restrict__ bf1v,
        const float* __restrict__ wtf2,
        const float* __restrict__ bf2v,
        float* __restrict__ out) {
    __shared__ float sf[256];
    const int b = blockIdx.x;
    const int j = threadIdx.x;
    float s = 0.f;
    #pragma unroll
    for (int p = 0; p < S; p++)
        s += parts[(long)p * 262144 + (long)b * 256 + j];
    const double c2 = scr[2];
    const float alpha = (float)(scr[1] / (c2 > 1.0 ? c2 : 1.0));
    sf[j] = fmaxf(alpha * s + bf1v[j], 0.f);
    __syncthreads();
    const int lane = threadIdx.x & 63, wid = threadIdx.x >> 6;
    for (int k = wid; k < 10; k += 4) {
        const float* wr = wtf2 + k * 256;
        float acc = 0.f;
        #pragma unroll
        for (int t = 0; t < 4; t++)
            acc += sf[lane + t * 64] * wr[lane + t * 64];
        #pragma unroll
        for (int off = 32; off > 0; off >>= 1)
            acc += __shfl_down(acc, off, 64);
        if (lane == 0) out[(long)b * 10 + k] = acc + bf2v[k];
    }
}

extern "C" void kernel_launch(void* const* d_in, const int* in_sizes, int n_in,
                              void* d_out, int out_size, void* d_ws, size_t ws_size,
                              hipStream_t stream) {
    const float* x   = (const float*)d_in[0];
    const float* w1  = (const float*)d_in[1];
    const float* b1  = (const float*)d_in[2];
    const float* w2  = (const float*)d_in[3];
    const float* b2  = (const float*)d_in[4];
    const float* w3  = (const float*)d_in[5];
    const float* b3  = (const float*)d_in[6];
    const float* wf1 = (const float*)d_in[7];
    const float* bf1 = (const float*)d_in[8];
    const float* wf2 = (const float*)d_in[9];
    const float* bf2 = (const float*)d_in[10];
    float* out = (float*)d_out;
    float* ws = (float*)d_ws;

    const int B = 1024;

    signed char*    w1b   = (signed char*)(ws + WS_W1B);
    signed char*    w2p8  = (signed char*)(ws + WS_W2P);
    signed char*    w3p8  = (signed char*)(ws + WS_W3P);
    unsigned short* wtf1b = (unsigned short*)(ws + WS_WTF1);
    float*          wtf2  = ws + WS_WTF2;
    float*          a1f   = ws + WS_A1;
    unsigned short* a2p   = (unsigned short*)(ws + WS_A2);
    unsigned short* a3p   = (unsigned short*)(ws + WS_A3);
    double*         scr   = (double*)(ws + WS_SCR);
    int*            iscr  = (int*)(scr + 20);
    int*            amaxx = iscr;           // amax(x)
    int*            amax1 = iscr + 1;       // amax(a1)
    int*            amax2 = iscr + 2;       // amax(a2)
    float*          parts = ws + WS_A1;     // alias: a1 dead after conv2

    hipMemsetAsync(scr, 0, 22 * sizeof(double), stream);
    hipMemsetAsync(w1b, 0, 8192, stream);   // BL/BH zero padding

    TernArgs ta;
    ta.w[0] = w1;  ta.n[0] = 64 * 27;
    ta.w[1] = w2;  ta.n[1] = 128 * 64 * 9;
    ta.w[2] = w3;  ta.n[2] = 256 * 128 * 9;
    ta.w[3] = wf1; ta.n[3] = 256 * 4096;
    ta.w[4] = wf2; ta.n[4] = 10 * 256;
    ta.w[5] = x;   ta.n[5] = 1024 * 3 * 32 * 32;   // amax(x)

    hipLaunchKernelGGL(tern_stats1, dim3(128, 6), dim3(256), 0, stream, ta, scr);
    hipLaunchKernelGGL(tern_stats2, dim3(128, 5), dim3(256), 0, stream, ta, scr);
    hipLaunchKernelGGL(tern_write_all, dim3(128, 5), dim3(256), 0, stream,
                       ta, scr, w1b, w2p8, w3p8, wtf1b, wtf2);

    // conv1: i8 MFMA, 1 block per image -> a1 fp32 rows + amax1
    hipLaunchKernelGGL(conv1_i8, dim3(B), dim3(256), 0, stream,
                       x, w1b, b1, scr + 0, amaxx, amax1, a1f);

    // conv2: CI=64, HI=16, CO=128, HB=2, fp32 input, NPH=1 -> 2048 blocks
    hipLaunchKernelGGL((conv_i8<64, 16, 128, 2, 2, 2, true, 1>), dim3(B * 2),
                       dim3(256), 0, stream, a1f, w2p8, b2, scr + 4, amax1,
                       amax2, a2p);

    // conv3: CI=128, HI=8, CO=256, HB=1, bf16-pair input, NPH=2 -> 1024 blocks
    hipLaunchKernelGGL((conv_i8<128, 8, 256, 1, 1, 4, false, 2>), dim3(B),
                       dim3(256), 0, stream, a2p, w3p8, b3, scr + 8, amax2,
                       (int*)nullptr, a3p);

    // fc1: MFMA split-K
    hipLaunchKernelGGL((fc1_mfma<FC1_S>), dim3(8, 2, FC1_S), dim3(256), 0, stream,
                       a3p, wtf1b, parts);

    // fused fc1-reduce + fc2
    hipLaunchKernelGGL((fc2_fused<FC1_S>), dim3(B), dim3(256), 0, stream,
                       parts, scr + 12, bf1, wtf2, bf2, out);
}